// Round 1
// baseline (2315.612 us; speedup 1.0000x reference)
//
#include <hip/hip_runtime.h>
#include <cmath>

// Problem constants
constexpr int Bb  = 512;            // batch
constexpr int Cc  = 12;             // leads (GRU seq len)
constexpr int Ww  = 4;              // windows
constexpr int Ff  = 512;            // features
constexpr int Nn  = Bb * Ww;        // 2048 merged GRU batch
constexpr int Gg  = 3 * Ff;         // 1536 gate width
constexpr int CWF = Cc * Ww * Ff;   // 24576 (x batch stride)
constexpr int WF  = Ww * Ff;        // 2048  (x lead stride)

__device__ __forceinline__ float sigm(float v) { return 1.f / (1.f + expf(-v)); }

// ---------------- K1: GRU step dual GEMM ----------------
// bufX[n,g] = bih[g] + sum_f x[b,t,w,f]*Wih[g,f]
// bufH[n,g] = bhh[g] + sum_f h[n,f]   *Whh[g,f]
// n = b*4 + w; tiles 64x64, BK=16; 256 thr, 4x4 micro-tile per GEMM.
__global__ __launch_bounds__(256) void gru_step_gemm(
    const float* __restrict__ x, const float* __restrict__ h,
    const float* __restrict__ wih, const float* __restrict__ whh,
    const float* __restrict__ bih, const float* __restrict__ bhh,
    float* __restrict__ bufX, float* __restrict__ bufH, int t)
{
    __shared__ float Ax[16][68], Ah[16][68], Bi[16][68], Bw[16][68];
    const int tid = threadIdx.x;
    const int g0 = blockIdx.x * 64;
    const int n0 = blockIdx.y * 64;
    const int lr = tid >> 2;          // 0..63 tile row
    const int lc = (tid & 3) << 2;    // k offset 0,4,8,12
    const int n  = n0 + lr;
    const int b  = n >> 2, w = n & 3;
    const float* xrow = x + b * CWF + t * WF + w * Ff;
    const float* hrow = h + n * Ff;
    const float* irow = wih + (g0 + lr) * Ff;
    const float* wrow = whh + (g0 + lr) * Ff;
    const int ty = tid >> 4, tx = tid & 15;

    float accX[4][4] = {{0.f}}, accH[4][4] = {{0.f}};

    for (int k0 = 0; k0 < Ff; k0 += 16) {
        float4 vx = *(const float4*)(xrow + k0 + lc);
        float4 vh = *(const float4*)(hrow + k0 + lc);
        float4 vi = *(const float4*)(irow + k0 + lc);
        float4 vw = *(const float4*)(wrow + k0 + lc);
        __syncthreads();
        Ax[lc+0][lr]=vx.x; Ax[lc+1][lr]=vx.y; Ax[lc+2][lr]=vx.z; Ax[lc+3][lr]=vx.w;
        Ah[lc+0][lr]=vh.x; Ah[lc+1][lr]=vh.y; Ah[lc+2][lr]=vh.z; Ah[lc+3][lr]=vh.w;
        Bi[lc+0][lr]=vi.x; Bi[lc+1][lr]=vi.y; Bi[lc+2][lr]=vi.z; Bi[lc+3][lr]=vi.w;
        Bw[lc+0][lr]=vw.x; Bw[lc+1][lr]=vw.y; Bw[lc+2][lr]=vw.z; Bw[lc+3][lr]=vw.w;
        __syncthreads();
        #pragma unroll
        for (int k = 0; k < 16; ++k) {
            const float4 a4x = *(const float4*)&Ax[k][ty*4];
            const float4 a4h = *(const float4*)&Ah[k][ty*4];
            const float4 b4i = *(const float4*)&Bi[k][tx*4];
            const float4 b4w = *(const float4*)&Bw[k][tx*4];
            const float axv[4] = {a4x.x, a4x.y, a4x.z, a4x.w};
            const float ahv[4] = {a4h.x, a4h.y, a4h.z, a4h.w};
            const float biv[4] = {b4i.x, b4i.y, b4i.z, b4i.w};
            const float bwv[4] = {b4w.x, b4w.y, b4w.z, b4w.w};
            #pragma unroll
            for (int i = 0; i < 4; ++i)
                #pragma unroll
                for (int j = 0; j < 4; ++j) {
                    accX[i][j] += axv[i] * biv[j];
                    accH[i][j] += ahv[i] * bwv[j];
                }
        }
    }
    #pragma unroll
    for (int i = 0; i < 4; ++i) {
        const int row = n0 + ty * 4 + i;
        const int col = g0 + tx * 4;
        float4 ox, oh;
        ox.x = accX[i][0] + bih[col+0]; ox.y = accX[i][1] + bih[col+1];
        ox.z = accX[i][2] + bih[col+2]; ox.w = accX[i][3] + bih[col+3];
        oh.x = accH[i][0] + bhh[col+0]; oh.y = accH[i][1] + bhh[col+1];
        oh.z = accH[i][2] + bhh[col+2]; oh.w = accH[i][3] + bhh[col+3];
        *(float4*)&bufX[row * Gg + col] = ox;
        *(float4*)&bufH[row * Gg + col] = oh;
    }
}

// ---------------- K2: GRU gate update ----------------
__global__ __launch_bounds__(256) void gru_update(
    const float* __restrict__ bufX, const float* __restrict__ bufH,
    float* __restrict__ h, float* __restrict__ gru_out, int t)
{
    const int idx = blockIdx.x * 256 + threadIdx.x;   // over Nn*Ff
    const int n = idx >> 9, f = idx & 511;
    const float* bx = bufX + n * Gg;
    const float* bh = bufH + n * Gg;
    const float r  = sigm(bx[f] + bh[f]);
    const float z  = sigm(bx[512 + f] + bh[512 + f]);
    const float nn = tanhf(bx[1024 + f] + r * bh[1024 + f]);
    const float hprev = h[idx];
    const float hnew  = (1.f - z) * nn + z * hprev;
    h[idx] = hnew;
    const int b = n >> 2, w = n & 3;
    gru_out[b * CWF + t * WF + w * Ff + f] = hnew;
}

// ---------------- K3: conv0 over windows + relu ----------------
__global__ __launch_bounds__(256) void conv0_relu(
    const float* __restrict__ gru_out, const float* __restrict__ w0,
    const float* __restrict__ b0, float* __restrict__ y1)
{
    const int idx = blockIdx.x * 256 + threadIdx.x;   // B*C*F
    const int f = idx & 511;
    const int bc = idx >> 9;
    const int b = bc / 12, c = bc - 12 * b;
    const float* g = gru_out + b * CWF + c * WF + f;
    float v = b0[0] + g[0] * w0[0] + g[512] * w0[1] + g[1024] * w0[2] + g[1536] * w0[3];
    y1[idx] = fmaxf(v, 0.f);
}

// ---------------- K4: conv1 reduce over F + relu ----------------
__global__ __launch_bounds__(256) void conv1_relu(
    const float* __restrict__ y1, const float* __restrict__ w1,
    const float* __restrict__ b1, float* __restrict__ y2)
{
    const int wave = (blockIdx.x * 256 + threadIdx.x) >> 6;  // row in [0, B*C)
    const int lane = threadIdx.x & 63;
    const float* row = y1 + wave * Ff;
    float s = 0.f;
    for (int f = lane; f < Ff; f += 64) s += row[f] * w1[f];
    #pragma unroll
    for (int off = 32; off; off >>= 1) s += __shfl_down(s, off);
    if (lane == 0) y2[wave] = fmaxf(s + b1[0], 0.f);
}

// ---------------- K5: conv2 + relu + mean over batch ----------------
__global__ __launch_bounds__(256) void conv2_mean(
    const float* __restrict__ y2, const float* __restrict__ w2,
    const float* __restrict__ b2, float* __restrict__ adjr)
{
    __shared__ float red[256];
    const int k = blockIdx.x;           // 0..143
    const int tid = threadIdx.x;
    float wk[12];
    #pragma unroll
    for (int c = 0; c < 12; ++c) wk[c] = w2[k * 12 + c];
    const float bias = b2[k];
    float part = 0.f;
    for (int b = tid; b < Bb; b += 256) {
        const float* yb = y2 + b * 12;
        float s = bias;
        #pragma unroll
        for (int c = 0; c < 12; ++c) s += yb[c] * wk[c];
        part += fmaxf(s, 0.f);
    }
    red[tid] = part; __syncthreads();
    for (int off = 128; off; off >>= 1) {
        if (tid < off) red[tid] += red[tid + off];
        __syncthreads();
    }
    if (tid == 0) adjr[k] = red[0] * (1.f / Bb);
}

// ---------------- K6: adjacency -> Laplacian -> Chebyshev (1 block) ----------------
__global__ __launch_bounds__(256) void build_cheb(
    const float* __restrict__ adjr, float* __restrict__ cheb)
{
    __shared__ float adj[12][12], deg[12], dhat[12], lap[12][12], T2[12][12];
    const int tid = threadIdx.x;
    if (tid < 144) adj[tid / 12][tid % 12] = fmaxf(adjr[tid], 0.f);
    __syncthreads();
    if (tid < 12) {
        float s = 0.f;
        for (int j = 0; j < 12; ++j) s += adj[tid][j];
        deg[tid] = s;
        dhat[tid] = 1.f / (sqrtf(s) + 1e-7f);
    }
    __syncthreads();
    if (tid < 144) {
        const int i = tid / 12, j = tid % 12;
        const float as = 0.5f * (adj[i][j] + adj[j][i]);
        lap[i][j] = dhat[i] * ((i == j ? deg[i] : 0.f) - as) * dhat[j];
    }
    __syncthreads();
    if (tid < 144) {
        const int i = tid / 12, j = tid % 12;
        float s = 0.f;
        for (int kk = 0; kk < 12; ++kk) s += lap[i][kk] * lap[kk][j];
        T2[i][j] = 2.f * s;
    }
    __syncthreads();
    if (tid < 144) {
        const int i = tid / 12, j = tid % 12;
        float s = 0.f;
        for (int kk = 0; kk < 12; ++kk) s += lap[i][kk] * T2[kk][j];
        const float t3 = 2.f * s - lap[i][j];
        cheb[tid]       = 0.f;        // L0
        cheb[144 + tid] = lap[i][j];  // L1
        cheb[288 + tid] = T2[i][j];   // L2
        cheb[432 + tid] = t3;         // L3
    }
}

// ---------------- K7: generic NN GEMM C = A @ B (+ optional bias/lrelu/BN) ----------------
// A: [M, lda] (or permuted gru_out view), B: [K, N] row-major, C: [M, N]
__global__ __launch_bounds__(256) void gemm_nn(
    const float* __restrict__ A, int lda, int permuted,
    const float* __restrict__ Bmat,
    float* __restrict__ Cout, int N, int K,
    const float* __restrict__ bias, int ep,
    const float* __restrict__ bng, const float* __restrict__ bnb,
    const float* __restrict__ bnm, const float* __restrict__ bnv)
{
    __shared__ float As[16][68], Bs[16][68];
    const int tid = threadIdx.x;
    const int n0 = blockIdx.x * 64, m0 = blockIdx.y * 64;
    const int lr = tid >> 2, lc = (tid & 3) << 2;
    const int m = m0 + lr;
    const float* arow;
    if (permuted) {  // A row m=(b*4+w)*12+c  ->  gru_out[b, c, w, :]
        const int b = m / 48, r = m - b * 48;
        const int w = r / 12, c = r - w * 12;
        arow = A + b * CWF + c * WF + w * Ff;
    } else {
        arow = A + (long)m * lda;
    }
    const int kr = tid >> 4, cc = (tid & 15) << 2;
    const int ty = tid >> 4, tx = tid & 15;
    float acc[4][4] = {{0.f}};

    for (int k0 = 0; k0 < K; k0 += 16) {
        float4 va = *(const float4*)(arow + k0 + lc);
        float4 vb = *(const float4*)(Bmat + (long)(k0 + kr) * N + n0 + cc);
        __syncthreads();
        As[lc+0][lr]=va.x; As[lc+1][lr]=va.y; As[lc+2][lr]=va.z; As[lc+3][lr]=va.w;
        *(float4*)&Bs[kr][cc] = vb;
        __syncthreads();
        #pragma unroll
        for (int k = 0; k < 16; ++k) {
            const float4 a4 = *(const float4*)&As[k][ty*4];
            const float4 b4 = *(const float4*)&Bs[k][tx*4];
            const float av[4] = {a4.x, a4.y, a4.z, a4.w};
            const float bv[4] = {b4.x, b4.y, b4.z, b4.w};
            #pragma unroll
            for (int i = 0; i < 4; ++i)
                #pragma unroll
                for (int j = 0; j < 4; ++j) acc[i][j] += av[i] * bv[j];
        }
    }
    #pragma unroll
    for (int i = 0; i < 4; ++i) {
        const int row = m0 + ty * 4 + i;
        const int col = n0 + tx * 4;
        float o[4];
        #pragma unroll
        for (int j = 0; j < 4; ++j) o[j] = acc[i][j];
        if (ep == 1) {
            #pragma unroll
            for (int j = 0; j < 4; ++j) {
                const int cj = col + j;
                float v = o[j] + bias[cj];
                v = v >= 0.f ? v : 0.01f * v;                      // leaky relu
                o[j] = (v - bnm[cj]) * rsqrtf(bnv[cj] + 1e-5f) * bng[cj] + bnb[cj];
            }
        }
        *(float4*)&Cout[(long)row * N + col] = make_float4(o[0], o[1], o[2], o[3]);
    }
}

// ---------------- K8: GCN cheb-mix epilogue ----------------
// layer1: H1[b,w,c,:] = relu(sum_j cheb[w,c,j]*S[b,w,j,:] + gcnb) + H0[b,w,c,:]
// layer2: pooled[b,c,:] = sum_w ( relu(...) + H1 + H0 )
__global__ __launch_bounds__(256) void gcn_epilogue(
    const float* __restrict__ S, const float* __restrict__ cheb,
    const float* __restrict__ gcnb, const float* __restrict__ gru_out,
    const float* __restrict__ H1in, float* __restrict__ outbuf, int layer2)
{
    __shared__ float ch[576];
    const int tid = threadIdx.x;
    for (int i = tid; i < 576; i += 256) ch[i] = cheb[i];
    __syncthreads();
    const int idx = blockIdx.x * 256 + tid;   // B*C*F
    const int f = idx & 511;
    const int bc = idx >> 9;
    const int b = bc / 12, c = bc - 12 * b;
    const float bias = gcnb[f];
    if (!layer2) {
        #pragma unroll
        for (int w = 0; w < 4; ++w) {
            float o = bias;
            const float* Srow = S + ((b * 4 + w) * 12) * 512 + f;
            const float* cw = ch + w * 144 + c * 12;
            #pragma unroll
            for (int j = 0; j < 12; ++j) o += cw[j] * Srow[j * 512];
            const float hv = fmaxf(o, 0.f) + gru_out[b * CWF + c * WF + w * Ff + f];
            outbuf[((b * 4 + w) * 12 + c) * 512 + f] = hv;
        }
    } else {
        float acc = 0.f;
        #pragma unroll
        for (int w = 0; w < 4; ++w) {
            float o = bias;
            const float* Srow = S + ((b * 4 + w) * 12) * 512 + f;
            const float* cw = ch + w * 144 + c * 12;
            #pragma unroll
            for (int j = 0; j < 12; ++j) o += cw[j] * Srow[j * 512];
            acc += fmaxf(o, 0.f) + H1in[((b * 4 + w) * 12 + c) * 512 + f]
                 + gru_out[b * CWF + c * WF + w * Ff + f];
        }
        outbuf[idx] = acc;   // pooled flat index = b*6144 + c*512 + f = idx
    }
}

// ---------------- K9: fc3 ----------------
__global__ __launch_bounds__(256) void fc3_kernel(
    const float* __restrict__ z2, const float* __restrict__ w3,
    const float* __restrict__ b3, float* __restrict__ out)
{
    const int idx = blockIdx.x * 256 + threadIdx.x;  // 2048
    const int m = idx >> 2, nc = idx & 3;
    float s = b3[nc];
    const float* zr = z2 + m * 512;
    for (int k = 0; k < 512; ++k) s += zr[k] * w3[k * 4 + nc];
    out[idx] = s;
}

extern "C" void kernel_launch(void* const* d_in, const int* in_sizes, int n_in,
                              void* d_out, int out_size, void* d_ws, size_t ws_size,
                              hipStream_t stream)
{
    (void)in_sizes; (void)n_in; (void)out_size; (void)ws_size;
    const float* x    = (const float*)d_in[0];
    const float* wih  = (const float*)d_in[1];
    const float* whh  = (const float*)d_in[2];
    const float* bih  = (const float*)d_in[3];
    const float* bhh  = (const float*)d_in[4];
    const float* c0w  = (const float*)d_in[5];
    const float* c0b  = (const float*)d_in[6];
    const float* c1w  = (const float*)d_in[7];
    const float* c1b  = (const float*)d_in[8];
    const float* c2w  = (const float*)d_in[9];
    const float* c2b  = (const float*)d_in[10];
    const float* gcnw = (const float*)d_in[11];
    const float* gcnb = (const float*)d_in[12];
    const float* f1w  = (const float*)d_in[13];
    const float* f1b  = (const float*)d_in[14];
    const float* bn1g = (const float*)d_in[15];
    const float* bn1b = (const float*)d_in[16];
    const float* bn1m = (const float*)d_in[17];
    const float* bn1v = (const float*)d_in[18];
    const float* f2w  = (const float*)d_in[19];
    const float* f2b  = (const float*)d_in[20];
    const float* bn2g = (const float*)d_in[21];
    const float* bn2b = (const float*)d_in[22];
    const float* bn2m = (const float*)d_in[23];
    const float* bn2v = (const float*)d_in[24];
    const float* f3w  = (const float*)d_in[25];
    const float* f3b  = (const float*)d_in[26];

    // Workspace layout (floats). Total ≈ 165.7 MB.
    float* ws      = (float*)d_ws;
    float* gru_out = ws;                       // 12,582,912  [B,C,W,F]
    float* S       = ws + 12582912;            // 12,582,912  [B,W,C,F] support; aliased: y1 (graph phase)
    float* H1      = ws + 25165824;            // 12,582,912  [B,W,C,F]; aliased: bufX/bufH (GRU phase)
    float* pooled  = ws + 37748736;            //  3,145,728  [B, C*F];  aliased: h state (GRU phase)
    float* bufX    = H1;                       //  3,145,728  [N, 3F]
    float* bufH    = H1 + 3145728;             //  3,145,728  [N, 3F]
    float* y1      = S;                        //  3,145,728  [B,C,F]
    float* h       = pooled;                   //  1,048,576  [N, F]
    float* y2      = ws + 40894464;            //  6,144
    float* adjr    = y2 + 6144;                //  144
    float* chebb   = adjr + 144;               //  576
    float* z1      = chebb + 576;              //  262,144
    float* z2      = z1 + 262144;              //  262,144

    // GRU: h0 = 0, 12 sequential steps
    hipMemsetAsync(h, 0, (size_t)Nn * Ff * sizeof(float), stream);
    for (int t = 0; t < Cc; ++t) {
        gru_step_gemm<<<dim3(Gg / 64, Nn / 64), 256, 0, stream>>>(
            x, h, wih, whh, bih, bhh, bufX, bufH, t);
        gru_update<<<(Nn * Ff) / 256, 256, 0, stream>>>(bufX, bufH, h, gru_out, t);
    }

    // GraphLearning -> Chebyshev basis
    conv0_relu<<<(Bb * Cc * Ff) / 256, 256, 0, stream>>>(gru_out, c0w, c0b, y1);
    conv1_relu<<<(Bb * Cc) / 4, 256, 0, stream>>>(y1, c1w, c1b, y2);
    conv2_mean<<<Cc * Cc, 256, 0, stream>>>(y2, c2w, c2b, adjr);
    build_cheb<<<1, 256, 0, stream>>>(adjr, chebb);

    // GCN layer 1: S = H0 @ gcn_w[0] (H0 = permuted gru_out view)
    gemm_nn<<<dim3(Ff / 64, (Bb * Ww * Cc) / 64), 256, 0, stream>>>(
        gru_out, 512, 1, gcnw, S, Ff, Ff, nullptr, 0, nullptr, nullptr, nullptr, nullptr);
    gcn_epilogue<<<(Bb * Cc * Ff) / 256, 256, 0, stream>>>(
        S, chebb, gcnb, gru_out, nullptr, H1, 0);

    // GCN layer 2: S = H1 @ gcn_w[1]; epilogue writes pooled = sum_w(H0 + relu(O2) + H1)
    gemm_nn<<<dim3(Ff / 64, (Bb * Ww * Cc) / 64), 256, 0, stream>>>(
        H1, 512, 0, gcnw + Ff * Ff, S, Ff, Ff, nullptr, 0, nullptr, nullptr, nullptr, nullptr);
    gcn_epilogue<<<(Bb * Cc * Ff) / 256, 256, 0, stream>>>(
        S, chebb, gcnb + Ff, gru_out, H1, pooled, 1);

    // Head: fc1 + lrelu + bn1 -> fc2 + lrelu + bn2 -> fc3
    gemm_nn<<<dim3(512 / 64, Bb / 64), 256, 0, stream>>>(
        pooled, Cc * Ff, 0, f1w, z1, 512, Cc * Ff, f1b, 1, bn1g, bn1b, bn1m, bn1v);
    gemm_nn<<<dim3(512 / 64, Bb / 64), 256, 0, stream>>>(
        z1, 512, 0, f2w, z2, 512, 512, f2b, 1, bn2g, bn2b, bn2m, bn2v);
    fc3_kernel<<<(Bb * 4) / 256, 256, 0, stream>>>(z2, f3w, f3b, (float*)d_out);
}

// Round 2
// 655.132 us; speedup vs baseline: 3.5346x; 3.5346x over previous
//
#include <hip/hip_runtime.h>
#include <cmath>

// ---- problem constants ----
constexpr int Bb  = 512;
constexpr int Cc  = 12;
constexpr int Ww  = 4;
constexpr int Ff  = 512;
constexpr int Nn  = Bb * Ww;        // 2048
constexpr int Gg  = 3 * Ff;         // 1536
constexpr int Mx  = Nn * Cc;        // 24576 rows for xW / GCN gemms

typedef __attribute__((ext_vector_type(8))) short bf16x8;
typedef __attribute__((ext_vector_type(4))) float f32x4;

__device__ __forceinline__ float sigm(float v) { return 1.f / (1.f + expf(-v)); }
__device__ __forceinline__ float b2f(ushort u) { union { float f; unsigned i; } v; v.i = ((unsigned)u) << 16; return v.f; }
__device__ __forceinline__ ushort f2b(float f) {
    union { float f; unsigned i; } v; v.f = f;
    unsigned r = v.i + 0x7FFFu + ((v.i >> 16) & 1u);
    return (ushort)(r >> 16);
}
__device__ __forceinline__ void async16(const ushort* g, ushort* l) {
    __builtin_amdgcn_global_load_lds(
        (const __attribute__((address_space(1))) unsigned int*)g,
        (__attribute__((address_space(3))) unsigned int*)l, 16, 0, 0);
}

// =============== generic bf16 MFMA GEMM (m97 structure) ===============
// C[M,N] = A[M,K] @ Bt[N,K]^T.  Block 128x128, 4 waves (64x64 each, 4x4 of 16x16x32).
// BK=64 chunks staged via global_load_lds(16B) into XOR-swizzled LDS (conflict-free).
// If Cb != null: store bf16.  Else fp32 at Cf + blockIdx.z*MN (split-K partials).
__global__ __launch_bounds__(256) void mfma_gemm(
    const ushort* __restrict__ A, const ushort* __restrict__ Bt,
    float* __restrict__ Cf, ushort* __restrict__ Cb,
    int N, int K, int kLen, int MN)
{
    __shared__ ushort As[128 * 64], Bs[128 * 64];
    const int tid = threadIdx.x;
    const int ln = tid & 63, wv = tid >> 6;
    const int srow = ln >> 3;                    // 0..7 row within 8-row chunk
    const int kslot = (ln & 7) ^ srow;           // swizzled k-group gathered by this lane
    const int rowA0 = blockIdx.y * 128 + wv * 32;
    const int rowB0 = blockIdx.x * 128 + wv * 32;
    const ushort* ga = A  + (long)(rowA0 + srow) * K + blockIdx.z * kLen + kslot * 8;
    const ushort* gb = Bt + (long)(rowB0 + srow) * K + blockIdx.z * kLen + kslot * 8;
    ushort* la = As + wv * 32 * 64;
    ushort* lb = Bs + wv * 32 * 64;
    const int rbase = (wv >> 1) * 64, cbase = (wv & 1) * 64;
    const int mrow = ln & 15, quad = ln >> 4;

    f32x4 acc[4][4] = {};

    for (int kc = 0; kc < kLen; kc += 64) {
        #pragma unroll
        for (int i = 0; i < 4; ++i) {
            async16(ga + (long)(i * 8) * K, la + i * 8 * 64);
            async16(gb + (long)(i * 8) * K, lb + i * 8 * 64);
        }
        ga += 64; gb += 64;
        __syncthreads();                          // drains vmcnt: staged data visible
        #pragma unroll
        for (int s = 0; s < 2; ++s) {
            const int sw = (((s << 2) + quad) ^ (ln & 7)) << 3;
            bf16x8 af[4], bf[4];
            #pragma unroll
            for (int i = 0; i < 4; ++i)
                af[i] = *(const bf16x8*)(As + (rbase + i * 16 + mrow) * 64 + sw);
            #pragma unroll
            for (int j = 0; j < 4; ++j)
                bf[j] = *(const bf16x8*)(Bs + (cbase + j * 16 + mrow) * 64 + sw);
            #pragma unroll
            for (int i = 0; i < 4; ++i)
                #pragma unroll
                for (int j = 0; j < 4; ++j)
                    acc[i][j] = __builtin_amdgcn_mfma_f32_16x16x32_bf16(af[i], bf[j], acc[i][j], 0, 0, 0);
        }
        __syncthreads();                          // WAR guard before next chunk overwrite
    }

    const int gr0 = blockIdx.y * 128 + rbase + quad * 4;
    const int gc0 = blockIdx.x * 128 + cbase + mrow;
    if (Cb) {
        #pragma unroll
        for (int i = 0; i < 4; ++i)
            #pragma unroll
            for (int r = 0; r < 4; ++r) {
                const int row = gr0 + i * 16 + r;
                #pragma unroll
                for (int j = 0; j < 4; ++j)
                    Cb[(long)row * N + gc0 + j * 16] = f2b(acc[i][j][r]);
            }
    } else {
        float* Co = Cf + (long)blockIdx.z * MN;
        #pragma unroll
        for (int i = 0; i < 4; ++i)
            #pragma unroll
            for (int r = 0; r < 4; ++r) {
                const int row = gr0 + i * 16 + r;
                #pragma unroll
                for (int j = 0; j < 4; ++j)
                    Co[(long)row * N + gc0 + j * 16] = acc[i][j][r];
            }
    }
}

// =============== conversions ===============
// x[b,c,w,f] fp32 -> xb[(b*4+w)*12+c][f] bf16
__global__ __launch_bounds__(256) void cvt_x(const float* __restrict__ x, ushort* __restrict__ xb)
{
    const int idx = blockIdx.x * 256 + threadIdx.x;   // Mx*64, 8 elems each
    const int m = idx >> 6, f8 = (idx & 63) << 3;
    const int n = m / 12, c = m - n * 12;
    const int b = n >> 2, w = n & 3;
    const float* src = x + (((b * 12 + c) * 4 + w) << 9) + f8;
    const float4 a = *(const float4*)src, q = *(const float4*)(src + 4);
    uint4 o;
    o.x = (unsigned)f2b(a.x) | ((unsigned)f2b(a.y) << 16);
    o.y = (unsigned)f2b(a.z) | ((unsigned)f2b(a.w) << 16);
    o.z = (unsigned)f2b(q.x) | ((unsigned)f2b(q.y) << 16);
    o.w = (unsigned)f2b(q.z) | ((unsigned)f2b(q.w) << 16);
    *(uint4*)(xb + (m << 9) + f8) = o;
}

// plain fp32 -> bf16, same layout (for wih/whh which are already [N][K])
__global__ __launch_bounds__(256) void cvt_mat(const float* __restrict__ src, ushort* __restrict__ dst)
{
    const int idx = blockIdx.x * 256 + threadIdx.x;   // elems/8
    const int e = idx << 3;
    const float4 a = *(const float4*)(src + e), q = *(const float4*)(src + e + 4);
    uint4 o;
    o.x = (unsigned)f2b(a.x) | ((unsigned)f2b(a.y) << 16);
    o.y = (unsigned)f2b(a.z) | ((unsigned)f2b(a.w) << 16);
    o.z = (unsigned)f2b(q.x) | ((unsigned)f2b(q.y) << 16);
    o.w = (unsigned)f2b(q.z) | ((unsigned)f2b(q.w) << 16);
    *(uint4*)(dst + e) = o;
}

// src fp32 [R][C] -> dst bf16 [C][R]
__global__ __launch_bounds__(256) void tcvt(const float* __restrict__ src, ushort* __restrict__ dst, int R, int C)
{
    __shared__ float t[32][33];
    const int c0 = blockIdx.x * 32, r0 = blockIdx.y * 32;
    const int cx = threadIdx.x & 31, ry = threadIdx.x >> 5;
    #pragma unroll
    for (int k = 0; k < 4; ++k) t[ry + k * 8][cx] = src[(long)(r0 + ry + k * 8) * C + c0 + cx];
    __syncthreads();
    #pragma unroll
    for (int k = 0; k < 4; ++k) dst[(long)(c0 + ry + k * 8) * R + r0 + cx] = f2b(t[cx][ry + k * 8]);
}

// =============== GRU gate update ===============
__global__ __launch_bounds__(256) void gru_update(
    const float* __restrict__ bufG, const ushort* __restrict__ xw,
    const float* __restrict__ bih, const float* __restrict__ bhh,
    ushort* __restrict__ h, ushort* __restrict__ G, int t)
{
    const int idx = blockIdx.x * 256 + threadIdx.x;   // Nn*Ff
    const int n = idx >> 9, f = idx & 511;
    const int m = n * 12 + t;
    const float xr = b2f(xw[m * 1536 + f])        + bih[f];
    const float xz = b2f(xw[m * 1536 + 512 + f])  + bih[512 + f];
    const float xn = b2f(xw[m * 1536 + 1024 + f]) + bih[1024 + f];
    const float hr = bufG[n * 1536 + f]        + bhh[f];
    const float hz = bufG[n * 1536 + 512 + f]  + bhh[512 + f];
    const float hn = bufG[n * 1536 + 1024 + f] + bhh[1024 + f];
    const float r = sigm(xr + hr), z = sigm(xz + hz);
    const float nv = tanhf(xn + r * hn);
    const float hv = (1.f - z) * nv + z * b2f(h[idx]);
    const ushort hb = f2b(hv);
    h[idx] = hb;
    G[m * 512 + f] = hb;
}

// =============== graph-learning ===============
__global__ __launch_bounds__(256) void conv0_relu(
    const ushort* __restrict__ G, const float* __restrict__ w0,
    const float* __restrict__ b0, float* __restrict__ y1)
{
    const int idx = blockIdx.x * 256 + threadIdx.x;   // B*C*F
    const int f = idx & 511, bc = idx >> 9;
    const int b = bc / 12, c = bc - 12 * b;
    const ushort* g = G + ((b * 4) * 12 + c) * 512 + f;   // w stride = 12*512
    float v = b0[0] + b2f(g[0]) * w0[0] + b2f(g[6144]) * w0[1]
            + b2f(g[12288]) * w0[2] + b2f(g[18432]) * w0[3];
    y1[idx] = fmaxf(v, 0.f);
}

__global__ __launch_bounds__(256) void conv1_relu(
    const float* __restrict__ y1, const float* __restrict__ w1,
    const float* __restrict__ b1, float* __restrict__ y2)
{
    const int wave = (blockIdx.x * 256 + threadIdx.x) >> 6;
    const int lane = threadIdx.x & 63;
    const float* row = y1 + wave * Ff;
    float s = 0.f;
    for (int f = lane; f < Ff; f += 64) s += row[f] * w1[f];
    #pragma unroll
    for (int off = 32; off; off >>= 1) s += __shfl_down(s, off);
    if (lane == 0) y2[wave] = fmaxf(s + b1[0], 0.f);
}

__global__ __launch_bounds__(256) void conv2_mean(
    const float* __restrict__ y2, const float* __restrict__ w2,
    const float* __restrict__ b2, float* __restrict__ adjr)
{
    __shared__ float red[256];
    const int k = blockIdx.x, tid = threadIdx.x;
    float wk[12];
    #pragma unroll
    for (int c = 0; c < 12; ++c) wk[c] = w2[k * 12 + c];
    const float bias = b2[k];
    float part = 0.f;
    for (int b = tid; b < Bb; b += 256) {
        const float* yb = y2 + b * 12;
        float s = bias;
        #pragma unroll
        for (int c = 0; c < 12; ++c) s += yb[c] * wk[c];
        part += fmaxf(s, 0.f);
    }
    red[tid] = part; __syncthreads();
    for (int off = 128; off; off >>= 1) { if (tid < off) red[tid] += red[tid + off]; __syncthreads(); }
    if (tid == 0) adjr[k] = red[0] * (1.f / Bb);
}

__global__ __launch_bounds__(256) void build_cheb(const float* __restrict__ adjr, float* __restrict__ cheb)
{
    __shared__ float adj[12][12], deg[12], dhat[12], lap[12][12], T2[12][12];
    const int tid = threadIdx.x;
    if (tid < 144) adj[tid / 12][tid % 12] = fmaxf(adjr[tid], 0.f);
    __syncthreads();
    if (tid < 12) {
        float s = 0.f;
        for (int j = 0; j < 12; ++j) s += adj[tid][j];
        deg[tid] = s; dhat[tid] = 1.f / (sqrtf(s) + 1e-7f);
    }
    __syncthreads();
    if (tid < 144) {
        const int i = tid / 12, j = tid % 12;
        const float as = 0.5f * (adj[i][j] + adj[j][i]);
        lap[i][j] = dhat[i] * ((i == j ? deg[i] : 0.f) - as) * dhat[j];
    }
    __syncthreads();
    if (tid < 144) {
        const int i = tid / 12, j = tid % 12;
        float s = 0.f;
        for (int kk = 0; kk < 12; ++kk) s += lap[i][kk] * lap[kk][j];
        T2[i][j] = 2.f * s;
    }
    __syncthreads();
    if (tid < 144) {
        const int i = tid / 12, j = tid % 12;
        float s = 0.f;
        for (int kk = 0; kk < 12; ++kk) s += lap[i][kk] * T2[kk][j];
        cheb[tid] = 0.f;
        cheb[144 + tid] = lap[i][j];
        cheb[288 + tid] = T2[i][j];
        cheb[432 + tid] = 2.f * s - lap[i][j];
    }
}

// =============== GCN epilogues ===============
__global__ __launch_bounds__(256) void gcn_epi1(
    const ushort* __restrict__ S, const float* __restrict__ cheb,
    const float* __restrict__ gcnb, const ushort* __restrict__ G,
    ushort* __restrict__ H1)
{
    __shared__ float ch[576];
    const int tid = threadIdx.x;
    for (int i = tid; i < 576; i += 256) ch[i] = cheb[i];
    __syncthreads();
    const int idx = blockIdx.x * 256 + tid;   // B*C*F
    const int f = idx & 511, bc = idx >> 9;
    const int b = bc / 12, c = bc - 12 * b;
    const float bias = gcnb[f];
    #pragma unroll
    for (int w = 0; w < 4; ++w) {
        float o = bias;
        const ushort* Sr = S + ((b * 4 + w) * 12) * 512 + f;
        const float* cw = ch + w * 144 + c * 12;
        #pragma unroll
        for (int j = 0; j < 12; ++j) o += cw[j] * b2f(Sr[j * 512]);
        const int gi = ((b * 4 + w) * 12 + c) * 512 + f;
        H1[gi] = f2b(fmaxf(o, 0.f) + b2f(G[gi]));
    }
}

__global__ __launch_bounds__(256) void gcn_epi2(
    const ushort* __restrict__ S, const float* __restrict__ cheb,
    const float* __restrict__ gcnb, const ushort* __restrict__ G,
    const ushort* __restrict__ H1, ushort* __restrict__ pooled)
{
    __shared__ float ch[576];
    const int tid = threadIdx.x;
    for (int i = tid; i < 576; i += 256) ch[i] = cheb[i];
    __syncthreads();
    const int idx = blockIdx.x * 256 + tid;
    const int f = idx & 511, bc = idx >> 9;
    const int b = bc / 12, c = bc - 12 * b;
    const float bias = gcnb[f];
    float acc = 0.f;
    #pragma unroll
    for (int w = 0; w < 4; ++w) {
        float o = bias;
        const ushort* Sr = S + ((b * 4 + w) * 12) * 512 + f;
        const float* cw = ch + w * 144 + c * 12;
        #pragma unroll
        for (int j = 0; j < 12; ++j) o += cw[j] * b2f(Sr[j * 512]);
        const int gi = ((b * 4 + w) * 12 + c) * 512 + f;
        acc += fmaxf(o, 0.f) + b2f(H1[gi]) + b2f(G[gi]);
    }
    pooled[idx] = f2b(acc);   // [b][c*512+f]
}

// =============== head epilogues ===============
__global__ __launch_bounds__(256) void fc_epi(
    const float* __restrict__ part, int nsplit, const float* __restrict__ bias,
    const float* __restrict__ g, const float* __restrict__ be,
    const float* __restrict__ mu, const float* __restrict__ var,
    ushort* __restrict__ outb, float* __restrict__ outf)
{
    const int idx = blockIdx.x * 256 + threadIdx.x;   // 512*512
    const int c = idx & 511;
    float s = bias[c];
    for (int k = 0; k < nsplit; ++k) s += part[k * 262144 + idx];
    s = s >= 0.f ? s : 0.01f * s;
    s = (s - mu[c]) * rsqrtf(var[c] + 1e-5f) * g[c] + be[c];
    if (outb) outb[idx] = f2b(s); else outf[idx] = s;
}

__global__ __launch_bounds__(256) void fc3_kernel(
    const float* __restrict__ z2, const float* __restrict__ w3,
    const float* __restrict__ b3, float* __restrict__ out)
{
    const int idx = blockIdx.x * 256 + threadIdx.x;  // 2048
    const int m = idx >> 2, nc = idx & 3;
    float s = b3[nc];
    const float* zr = z2 + m * 512;
    for (int k = 0; k < 512; ++k) s += zr[k] * w3[k * 4 + nc];
    out[idx] = s;
}

extern "C" void kernel_launch(void* const* d_in, const int* in_sizes, int n_in,
                              void* d_out, int out_size, void* d_ws, size_t ws_size,
                              hipStream_t stream)
{
    (void)in_sizes; (void)n_in; (void)out_size; (void)ws_size;
    const float* x    = (const float*)d_in[0];
    const float* wih  = (const float*)d_in[1];
    const float* whh  = (const float*)d_in[2];
    const float* bih  = (const float*)d_in[3];
    const float* bhh  = (const float*)d_in[4];
    const float* c0w  = (const float*)d_in[5];
    const float* c0b  = (const float*)d_in[6];
    const float* c1w  = (const float*)d_in[7];
    const float* c1b  = (const float*)d_in[8];
    const float* c2w  = (const float*)d_in[9];
    const float* c2b  = (const float*)d_in[10];
    const float* gcnw = (const float*)d_in[11];
    const float* gcnb = (const float*)d_in[12];
    const float* f1w  = (const float*)d_in[13];
    const float* f1b  = (const float*)d_in[14];
    const float* bn1g = (const float*)d_in[15];
    const float* bn1b = (const float*)d_in[16];
    const float* bn1m = (const float*)d_in[17];
    const float* bn1v = (const float*)d_in[18];
    const float* f2w  = (const float*)d_in[19];
    const float* f2b_ = (const float*)d_in[20];
    const float* bn2g = (const float*)d_in[21];
    const float* bn2b = (const float*)d_in[22];
    const float* bn2m = (const float*)d_in[23];
    const float* bn2v = (const float*)d_in[24];
    const float* f3w  = (const float*)d_in[25];
    const float* f3b  = (const float*)d_in[26];

    // ---- workspace layout (bytes), aggressively aliased; total ~157.3 MB ----
    char* W = (char*)d_ws;
    ushort* xw     = (ushort*)(W + 0);             // 75,497,472  (dead after GRU)
    ushort* S      = (ushort*)(W + 0);             // 25,165,824  (alias xw)
    ushort* H1     = (ushort*)(W + 33554432);      // 25,165,824  (alias xw)
    ushort* xb     = (ushort*)(W + 75497472);      // 25,165,824  (dead after xW gemm)
    float*  y1     = (float*)(W + 75497472);       // 12,582,912  (alias xb)
    ushort* pooled = (ushort*)(W + 75497472 + 12582912); // 6,291,456
    ushort* G      = (ushort*)(W + 100663296);     // 25,165,824
    ushort* h      = (ushort*)(W + 125829120);     //  2,097,152
    float*  bufG   = (float*)(W + 127926272);      // 12,582,912 (region 16.8MB)
    float*  z1p    = (float*)(W + 127926272);      // 16,777,216 (alias bufG)
    float*  z2p    = (float*)(W + 127926272);      //  4,194,304 (alias z1p, after consumed)
    ushort* wihB   = (ushort*)(W + 144703488);     //  1,572,864
    ushort* whhB   = (ushort*)(W + 146276352);     //  1,572,864
    ushort* gw0    = (ushort*)(W + 147849216);     //    524,288
    ushort* gw1    = (ushort*)(W + 148373504);     //    524,288
    ushort* f1t    = (ushort*)(W + 148897792);     //  6,291,456
    ushort* f2t    = (ushort*)(W + 155189248);     //    524,288
    ushort* z1b    = (ushort*)(W + 155713536);     //    524,288
    float*  z2     = (float*)(W + 156237824);      //  1,048,576
    float*  y2     = (float*)(W + 157286400);      //     24,576
    float*  adjr   = (float*)(W + 157310976);      //      1,024
    float*  chebb  = (float*)(W + 157312000);      //      4,096

    // ---- conversions ----
    hipMemsetAsync(h, 0, (size_t)Nn * Ff * sizeof(ushort), stream);
    cvt_x<<<(Mx * 64) / 256, 256, 0, stream>>>(x, xb);
    cvt_mat<<<(Gg * Ff / 8) / 256, 256, 0, stream>>>(wih, wihB);
    cvt_mat<<<(Gg * Ff / 8) / 256, 256, 0, stream>>>(whh, whhB);
    tcvt<<<dim3(16, 16), 256, 0, stream>>>(gcnw, gw0, 512, 512);
    tcvt<<<dim3(16, 16), 256, 0, stream>>>(gcnw + 262144, gw1, 512, 512);
    tcvt<<<dim3(16, 192), 256, 0, stream>>>(f1w, f1t, 6144, 512);
    tcvt<<<dim3(16, 16), 256, 0, stream>>>(f2w, f2t, 512, 512);

    // ---- xW precompute: [24576,1536] = xb @ wihB^T ----
    mfma_gemm<<<dim3(Gg / 128, Mx / 128, 1), 256, 0, stream>>>(
        xb, wihB, nullptr, xw, Gg, Ff, Ff, 0);

    // ---- GRU: 12 sequential steps (h-gemm + fused gate update) ----
    for (int t = 0; t < Cc; ++t) {
        mfma_gemm<<<dim3(Gg / 128, Nn / 128, 1), 256, 0, stream>>>(
            h, whhB, bufG, nullptr, Gg, Ff, Ff, 0);
        gru_update<<<(Nn * Ff) / 256, 256, 0, stream>>>(bufG, xw, bih, bhh, h, G, t);
    }

    // ---- graph learning ----
    conv0_relu<<<(Bb * Cc * Ff) / 256, 256, 0, stream>>>(G, c0w, c0b, y1);
    conv1_relu<<<(Bb * Cc) / 4, 256, 0, stream>>>(y1, c1w, c1b, y2);
    conv2_mean<<<Cc * Cc, 256, 0, stream>>>(y2, c2w, c2b, adjr);
    build_cheb<<<1, 256, 0, stream>>>(adjr, chebb);

    // ---- GCN layer 1 ----
    mfma_gemm<<<dim3(Ff / 128, Mx / 128, 1), 256, 0, stream>>>(
        G, gw0, nullptr, S, Ff, Ff, Ff, 0);
    gcn_epi1<<<(Bb * Cc * Ff) / 256, 256, 0, stream>>>(S, chebb, gcnb, G, H1);

    // ---- GCN layer 2 + pool ----
    mfma_gemm<<<dim3(Ff / 128, Mx / 128, 1), 256, 0, stream>>>(
        H1, gw1, nullptr, S, Ff, Ff, Ff, 0);
    gcn_epi2<<<(Bb * Cc * Ff) / 256, 256, 0, stream>>>(S, chebb, gcnb + Ff, G, H1, pooled);

    // ---- head ----
    mfma_gemm<<<dim3(4, 4, 16), 256, 0, stream>>>(          // fc1 split-K 16
        pooled, f1t, z1p, nullptr, 512, Cc * Ff, 384, 262144);
    fc_epi<<<1024, 256, 0, stream>>>(z1p, 16, f1b, bn1g, bn1b, bn1m, bn1v, z1b, nullptr);
    mfma_gemm<<<dim3(4, 4, 4), 256, 0, stream>>>(           // fc2 split-K 4
        z1b, f2t, z2p, nullptr, 512, 512, 128, 262144);
    fc_epi<<<1024, 256, 0, stream>>>(z2p, 4, f2b_, bn2g, bn2b, bn2m, bn2v, nullptr, z2);
    fc3_kernel<<<(Bb * 4) / 256, 256, 0, stream>>>(z2, f3w, f3b, (float*)d_out);
}

// Round 3
// 522.707 us; speedup vs baseline: 4.4300x; 1.2533x over previous
//
#include <hip/hip_runtime.h>
#include <cmath>

// ---- problem constants ----
constexpr int Bb  = 512;
constexpr int Cc  = 12;
constexpr int Ww  = 4;
constexpr int Ff  = 512;
constexpr int Nn  = Bb * Ww;        // 2048
constexpr int Gg  = 3 * Ff;         // 1536
constexpr int Mx  = Nn * Cc;        // 24576

typedef __attribute__((ext_vector_type(8))) short bf16x8;
typedef __attribute__((ext_vector_type(4))) float f32x4;

__device__ __forceinline__ float sigm(float v) { return 1.f / (1.f + expf(-v)); }
__device__ __forceinline__ float b2f(ushort u) { union { float f; unsigned i; } v; v.i = ((unsigned)u) << 16; return v.f; }
__device__ __forceinline__ ushort f2b(float f) {
    union { float f; unsigned i; } v; v.f = f;
    unsigned r = v.i + 0x7FFFu + ((v.i >> 16) & 1u);
    return (ushort)(r >> 16);
}
__device__ __forceinline__ void async16(const ushort* g, ushort* l) {
    __builtin_amdgcn_global_load_lds(
        (const __attribute__((address_space(1))) unsigned int*)g,
        (__attribute__((address_space(3))) unsigned int*)l, 16, 0, 0);
}

// =============== generic bf16 MFMA GEMM ===============
// C[M,N] = A[M,K] @ Bt[N,K]^T.  Block 128x128, 4 waves.
// 1D grid: l = blockIdx.x; by = l % gridY (M-block, fastest), bx = l / gridY.
// Same-A blocks spaced gridY apart; gridY % 8 == 0 keeps them on one XCD L2.
__global__ __launch_bounds__(256) void mfma_gemm(
    const ushort* __restrict__ A, const ushort* __restrict__ Bt,
    float* __restrict__ Cf, ushort* __restrict__ Cb,
    const float* __restrict__ colBias,
    int N, int K, int kLen, int MN, int gridY)
{
    __shared__ ushort As[128 * 64], Bs[128 * 64];
    const int tid = threadIdx.x;
    const int ln = tid & 63, wv = tid >> 6;
    const int l = blockIdx.x;
    const int by = l % gridY, bx = l / gridY, bz = blockIdx.y;
    const int srow = ln >> 3;
    const int kslot = (ln & 7) ^ srow;
    const int rowA0 = by * 128 + wv * 32;
    const int rowB0 = bx * 128 + wv * 32;
    const ushort* ga = A  + (long)(rowA0 + srow) * K + bz * kLen + kslot * 8;
    const ushort* gb = Bt + (long)(rowB0 + srow) * K + bz * kLen + kslot * 8;
    ushort* la = As + wv * 32 * 64;
    ushort* lb = Bs + wv * 32 * 64;
    const int rbase = (wv >> 1) * 64, cbase = (wv & 1) * 64;
    const int mrow = ln & 15, quad = ln >> 4;

    f32x4 acc[4][4] = {};

    for (int kc = 0; kc < kLen; kc += 64) {
        #pragma unroll
        for (int i = 0; i < 4; ++i) {
            async16(ga + (long)(i * 8) * K, la + i * 8 * 64);
            async16(gb + (long)(i * 8) * K, lb + i * 8 * 64);
        }
        ga += 64; gb += 64;
        __syncthreads();
        #pragma unroll
        for (int s = 0; s < 2; ++s) {
            const int sw = (((s << 2) + quad) ^ (ln & 7)) << 3;
            bf16x8 af[4], bf[4];
            #pragma unroll
            for (int i = 0; i < 4; ++i)
                af[i] = *(const bf16x8*)(As + (rbase + i * 16 + mrow) * 64 + sw);
            #pragma unroll
            for (int j = 0; j < 4; ++j)
                bf[j] = *(const bf16x8*)(Bs + (cbase + j * 16 + mrow) * 64 + sw);
            #pragma unroll
            for (int i = 0; i < 4; ++i)
                #pragma unroll
                for (int j = 0; j < 4; ++j)
                    acc[i][j] = __builtin_amdgcn_mfma_f32_16x16x32_bf16(af[i], bf[j], acc[i][j], 0, 0, 0);
        }
        __syncthreads();
    }

    const int gr0 = by * 128 + rbase + quad * 4;
    const int gc0 = bx * 128 + cbase + mrow;
    if (Cb) {
        float cb[4] = {0.f, 0.f, 0.f, 0.f};
        if (colBias) {
            #pragma unroll
            for (int j = 0; j < 4; ++j) cb[j] = colBias[gc0 + j * 16];
        }
        #pragma unroll
        for (int i = 0; i < 4; ++i)
            #pragma unroll
            for (int r = 0; r < 4; ++r) {
                const int row = gr0 + i * 16 + r;
                #pragma unroll
                for (int j = 0; j < 4; ++j)
                    Cb[(long)row * N + gc0 + j * 16] = f2b(acc[i][j][r] + cb[j]);
            }
    } else {
        float* Co = Cf + (long)bz * MN;
        #pragma unroll
        for (int i = 0; i < 4; ++i)
            #pragma unroll
            for (int r = 0; r < 4; ++r) {
                const int row = gr0 + i * 16 + r;
                #pragma unroll
                for (int j = 0; j < 4; ++j)
                    Co[(long)row * N + gc0 + j * 16] = acc[i][j][r];
            }
    }
}

// =============== fused GRU step ===============
// gates = hin @ whhB^T; combine with xw (biases pre-folded: r,z get bih+bhh, n gets bih);
// write hout and G. Block: 256 thr, 64 rows x 32 f (x 3 gates = 96 cols). Grid 512 (m fastest).
__global__ __launch_bounds__(256) void gru_fused(
    const ushort* __restrict__ hin, const ushort* __restrict__ whhB,
    const ushort* __restrict__ xw, const float* __restrict__ bhh,
    ushort* __restrict__ hout, ushort* __restrict__ G, int t)
{
    __shared__ ushort As[64 * 64], Bs[96 * 64];
    const int tid = threadIdx.x, ln = tid & 63, wv = tid >> 6;
    const int l = blockIdx.x;
    const int mb = l & 31, fb = l >> 5;
    const int srow = ln >> 3, kslot = (ln & 7) ^ srow;
    const int mrow = ln & 15, quad = ln >> 4;
    f32x4 acc[6] = {};
    const ushort* ha = hin + (long)(mb * 64) * 512;

    for (int kc = 0; kc < 512; kc += 64) {
        #pragma unroll
        for (int a = 0; a < 2; ++a) {
            const int r0 = (wv * 2 + a) * 8;
            async16(ha + (long)(r0 + srow) * 512 + kc + kslot * 8, As + r0 * 64);
        }
        #pragma unroll
        for (int b8 = 0; b8 < 3; ++b8) {
            const int lr0 = (wv * 3 + b8) * 8;
            const int lr = lr0 + srow;
            const int g = lr >> 5, fc = lr & 31;
            async16(whhB + (long)(g * 512 + fb * 32 + fc) * 512 + kc + kslot * 8, Bs + lr0 * 64);
        }
        __syncthreads();
        #pragma unroll
        for (int s = 0; s < 2; ++s) {
            const int sw = (((s << 2) + quad) ^ (ln & 7)) << 3;
            const bf16x8 a = *(const bf16x8*)(As + (wv * 16 + mrow) * 64 + sw);
            #pragma unroll
            for (int jt = 0; jt < 6; ++jt) {   // jt = gate*2 + f_subtile
                const bf16x8 b = *(const bf16x8*)(Bs + (jt * 16 + mrow) * 64 + sw);
                acc[jt] = __builtin_amdgcn_mfma_f32_16x16x32_bf16(a, b, acc[jt], 0, 0, 0);
            }
        }
        __syncthreads();
    }

    #pragma unroll
    for (int ft = 0; ft < 2; ++ft) {
        const int f = fb * 32 + ft * 16 + mrow;
        const float bhn = bhh[1024 + f];
        #pragma unroll
        for (int r = 0; r < 4; ++r) {
            const int n = mb * 64 + wv * 16 + quad * 4 + r;
            const long xbase = (long)(n * 12 + t) * 1536 + f;
            const float xr = b2f(xw[xbase]);
            const float xz = b2f(xw[xbase + 512]);
            const float xn = b2f(xw[xbase + 1024]);
            const float rr = sigm(xr + acc[ft][r]);
            const float zz = sigm(xz + acc[2 + ft][r]);
            const float nv = tanhf(xn + rr * (acc[4 + ft][r] + bhn));
            const float hv = (1.f - zz) * nv + zz * b2f(hin[(long)n * 512 + f]);
            const ushort hb = f2b(hv);
            hout[(long)n * 512 + f] = hb;
            G[(long)(n * 12 + t) * 512 + f] = hb;
        }
    }
}

// =============== conversions ===============
__global__ __launch_bounds__(256) void cvt_x(const float* __restrict__ x, ushort* __restrict__ xb)
{
    const int idx = blockIdx.x * 256 + threadIdx.x;   // Mx*64
    const int m = idx >> 6, f8 = (idx & 63) << 3;
    const int n = m / 12, c = m - n * 12;
    const int b = n >> 2, w = n & 3;
    const float* src = x + (((b * 12 + c) * 4 + w) << 9) + f8;
    const float4 a = *(const float4*)src, q = *(const float4*)(src + 4);
    uint4 o;
    o.x = (unsigned)f2b(a.x) | ((unsigned)f2b(a.y) << 16);
    o.y = (unsigned)f2b(a.z) | ((unsigned)f2b(a.w) << 16);
    o.z = (unsigned)f2b(q.x) | ((unsigned)f2b(q.y) << 16);
    o.w = (unsigned)f2b(q.z) | ((unsigned)f2b(q.w) << 16);
    *(uint4*)(xb + (m << 9) + f8) = o;
}

__global__ __launch_bounds__(256) void cvt_mat(const float* __restrict__ src, ushort* __restrict__ dst)
{
    const int idx = blockIdx.x * 256 + threadIdx.x;
    const int e = idx << 3;
    const float4 a = *(const float4*)(src + e), q = *(const float4*)(src + e + 4);
    uint4 o;
    o.x = (unsigned)f2b(a.x) | ((unsigned)f2b(a.y) << 16);
    o.y = (unsigned)f2b(a.z) | ((unsigned)f2b(a.w) << 16);
    o.z = (unsigned)f2b(q.x) | ((unsigned)f2b(q.y) << 16);
    o.w = (unsigned)f2b(q.z) | ((unsigned)f2b(q.w) << 16);
    *(uint4*)(dst + e) = o;
}

__global__ __launch_bounds__(256) void tcvt(const float* __restrict__ src, ushort* __restrict__ dst, int R, int C)
{
    __shared__ float t[32][33];
    const int c0 = blockIdx.x * 32, r0 = blockIdx.y * 32;
    const int cx = threadIdx.x & 31, ry = threadIdx.x >> 5;
    #pragma unroll
    for (int k = 0; k < 4; ++k) t[ry + k * 8][cx] = src[(long)(r0 + ry + k * 8) * C + c0 + cx];
    __syncthreads();
    #pragma unroll
    for (int k = 0; k < 4; ++k) dst[(long)(c0 + ry + k * 8) * R + r0 + cx] = f2b(t[cx][ry + k * 8]);
}

__global__ __launch_bounds__(256) void bias_combo(
    const float* __restrict__ bih, const float* __restrict__ bhh, float* __restrict__ out)
{
    const int i = blockIdx.x * 256 + threadIdx.x;   // 1536
    out[i] = bih[i] + (i < 1024 ? bhh[i] : 0.f);
}

// =============== graph-learning (conv0+conv1 fused) ===============
__global__ __launch_bounds__(256) void conv01(
    const ushort* __restrict__ G, const float* __restrict__ w0, const float* __restrict__ b0,
    const float* __restrict__ w1, const float* __restrict__ b1, float* __restrict__ y2)
{
    const int row = (blockIdx.x * 256 + threadIdx.x) >> 6;   // b*12+c
    const int lane = threadIdx.x & 63;
    const int b = row / 12, c = row - 12 * b;
    const float w00 = w0[0], w01 = w0[1], w02 = w0[2], w03 = w0[3], bb = b0[0];
    const ushort* gp = G + ((long)(b * 4) * 12 + c) * 512;
    float s = 0.f;
    for (int f = lane; f < 512; f += 64) {
        const float v = bb + b2f(gp[f]) * w00 + b2f(gp[6144 + f]) * w01
                      + b2f(gp[12288 + f]) * w02 + b2f(gp[18432 + f]) * w03;
        s += fmaxf(v, 0.f) * w1[f];
    }
    #pragma unroll
    for (int off = 32; off; off >>= 1) s += __shfl_down(s, off);
    if (lane == 0) y2[row] = fmaxf(s + b1[0], 0.f);
}

__global__ __launch_bounds__(256) void conv2_mean(
    const float* __restrict__ y2, const float* __restrict__ w2,
    const float* __restrict__ b2, float* __restrict__ adjr)
{
    __shared__ float red[256];
    const int k = blockIdx.x, tid = threadIdx.x;
    float wk[12];
    #pragma unroll
    for (int c = 0; c < 12; ++c) wk[c] = w2[k * 12 + c];
    const float bias = b2[k];
    float part = 0.f;
    for (int b = tid; b < Bb; b += 256) {
        const float* yb = y2 + b * 12;
        float s = bias;
        #pragma unroll
        for (int c = 0; c < 12; ++c) s += yb[c] * wk[c];
        part += fmaxf(s, 0.f);
    }
    red[tid] = part; __syncthreads();
    for (int off = 128; off; off >>= 1) { if (tid < off) red[tid] += red[tid + off]; __syncthreads(); }
    if (tid == 0) adjr[k] = red[0] * (1.f / Bb);
}

__global__ __launch_bounds__(256) void build_cheb(const float* __restrict__ adjr, float* __restrict__ cheb)
{
    __shared__ float adj[12][12], deg[12], dhat[12], lap[12][12], T2[12][12];
    const int tid = threadIdx.x;
    if (tid < 144) adj[tid / 12][tid % 12] = fmaxf(adjr[tid], 0.f);
    __syncthreads();
    if (tid < 12) {
        float s = 0.f;
        for (int j = 0; j < 12; ++j) s += adj[tid][j];
        deg[tid] = s; dhat[tid] = 1.f / (sqrtf(s) + 1e-7f);
    }
    __syncthreads();
    if (tid < 144) {
        const int i = tid / 12, j = tid % 12;
        const float as = 0.5f * (adj[i][j] + adj[j][i]);
        lap[i][j] = dhat[i] * ((i == j ? deg[i] : 0.f) - as) * dhat[j];
    }
    __syncthreads();
    if (tid < 144) {
        const int i = tid / 12, j = tid % 12;
        float s = 0.f;
        for (int kk = 0; kk < 12; ++kk) s += lap[i][kk] * lap[kk][j];
        T2[i][j] = 2.f * s;
    }
    __syncthreads();
    if (tid < 144) {
        const int i = tid / 12, j = tid % 12;
        float s = 0.f;
        for (int kk = 0; kk < 12; ++kk) s += lap[i][kk] * T2[kk][j];
        cheb[tid] = 0.f;
        cheb[144 + tid] = lap[i][j];
        cheb[288 + tid] = T2[i][j];
        cheb[432 + tid] = 2.f * s - lap[i][j];
    }
}

// =============== GCN epilogues ===============
__global__ __launch_bounds__(256) void gcn_epi1(
    const ushort* __restrict__ S, const float* __restrict__ cheb,
    const float* __restrict__ gcnb, const ushort* __restrict__ G,
    ushort* __restrict__ H1)
{
    __shared__ float ch[576];
    const int tid = threadIdx.x;
    for (int i = tid; i < 576; i += 256) ch[i] = cheb[i];
    __syncthreads();
    const int idx = blockIdx.x * 256 + tid;
    const int f = idx & 511, bc = idx >> 9;
    const int b = bc / 12, c = bc - 12 * b;
    const float bias = gcnb[f];
    #pragma unroll
    for (int w = 0; w < 4; ++w) {
        float o = bias;
        const ushort* Sr = S + ((b * 4 + w) * 12) * 512 + f;
        const float* cw = ch + w * 144 + c * 12;
        #pragma unroll
        for (int j = 0; j < 12; ++j) o += cw[j] * b2f(Sr[j * 512]);
        const int gi = ((b * 4 + w) * 12 + c) * 512 + f;
        H1[gi] = f2b(fmaxf(o, 0.f) + b2f(G[gi]));
    }
}

__global__ __launch_bounds__(256) void gcn_epi2(
    const ushort* __restrict__ S, const float* __restrict__ cheb,
    const float* __restrict__ gcnb, const ushort* __restrict__ G,
    const ushort* __restrict__ H1, ushort* __restrict__ pooled)
{
    __shared__ float ch[576];
    const int tid = threadIdx.x;
    for (int i = tid; i < 576; i += 256) ch[i] = cheb[i];
    __syncthreads();
    const int idx = blockIdx.x * 256 + tid;
    const int f = idx & 511, bc = idx >> 9;
    const int b = bc / 12, c = bc - 12 * b;
    const float bias = gcnb[f];
    float acc = 0.f;
    #pragma unroll
    for (int w = 0; w < 4; ++w) {
        float o = bias;
        const ushort* Sr = S + ((b * 4 + w) * 12) * 512 + f;
        const float* cw = ch + w * 144 + c * 12;
        #pragma unroll
        for (int j = 0; j < 12; ++j) o += cw[j] * b2f(Sr[j * 512]);
        const int gi = ((b * 4 + w) * 12 + c) * 512 + f;
        acc += fmaxf(o, 0.f) + b2f(H1[gi]) + b2f(G[gi]);
    }
    pooled[idx] = f2b(acc);
}

// =============== head epilogues ===============
__global__ __launch_bounds__(256) void fc_epi(
    const float* __restrict__ part, int nsplit, const float* __restrict__ bias,
    const float* __restrict__ g, const float* __restrict__ be,
    const float* __restrict__ mu, const float* __restrict__ var,
    ushort* __restrict__ outb, float* __restrict__ outf)
{
    const int idx = blockIdx.x * 256 + threadIdx.x;
    const int c = idx & 511;
    float s = bias[c];
    for (int k = 0; k < nsplit; ++k) s += part[k * 262144 + idx];
    s = s >= 0.f ? s : 0.01f * s;
    s = (s - mu[c]) * rsqrtf(var[c] + 1e-5f) * g[c] + be[c];
    if (outb) outb[idx] = f2b(s); else outf[idx] = s;
}

__global__ __launch_bounds__(256) void fc3_kernel(
    const float* __restrict__ z2, const float* __restrict__ w3,
    const float* __restrict__ b3, float* __restrict__ out)
{
    const int idx = blockIdx.x * 256 + threadIdx.x;
    const int m = idx >> 2, nc = idx & 3;
    float s = b3[nc];
    const float* zr = z2 + m * 512;
    for (int k = 0; k < 512; ++k) s += zr[k] * w3[k * 4 + nc];
    out[idx] = s;
}

extern "C" void kernel_launch(void* const* d_in, const int* in_sizes, int n_in,
                              void* d_out, int out_size, void* d_ws, size_t ws_size,
                              hipStream_t stream)
{
    (void)in_sizes; (void)n_in; (void)out_size; (void)ws_size;
    const float* x    = (const float*)d_in[0];
    const float* wih  = (const float*)d_in[1];
    const float* whh  = (const float*)d_in[2];
    const float* bih  = (const float*)d_in[3];
    const float* bhh  = (const float*)d_in[4];
    const float* c0w  = (const float*)d_in[5];
    const float* c0b  = (const float*)d_in[6];
    const float* c1w  = (const float*)d_in[7];
    const float* c1b  = (const float*)d_in[8];
    const float* c2w  = (const float*)d_in[9];
    const float* c2b  = (const float*)d_in[10];
    const float* gcnw = (const float*)d_in[11];
    const float* gcnb = (const float*)d_in[12];
    const float* f1w  = (const float*)d_in[13];
    const float* f1b  = (const float*)d_in[14];
    const float* bn1g = (const float*)d_in[15];
    const float* bn1b = (const float*)d_in[16];
    const float* bn1m = (const float*)d_in[17];
    const float* bn1v = (const float*)d_in[18];
    const float* f2w  = (const float*)d_in[19];
    const float* f2b_ = (const float*)d_in[20];
    const float* bn2g = (const float*)d_in[21];
    const float* bn2b = (const float*)d_in[22];
    const float* bn2m = (const float*)d_in[23];
    const float* bn2v = (const float*)d_in[24];
    const float* f3w  = (const float*)d_in[25];
    const float* f3b  = (const float*)d_in[26];

    // ---- workspace layout (bytes), aliased; total ~141 MB ----
    char* W = (char*)d_ws;
    ushort* xw     = (ushort*)(W + 0);             // 75.5 MB (dead after GRU)
    ushort* S      = (ushort*)(W + 0);             // 25.2 MB (alias xw)
    ushort* H1     = (ushort*)(W + 33554432);      // 25.2 MB (alias xw)
    ushort* xb     = (ushort*)(W + 75497472);      // 25.2 MB (dead after xW gemm)
    ushort* pooled = (ushort*)(W + 75497472);      //  6.3 MB (alias xb)
    float*  z1p    = (float*)(W + 81788928);       // 16.8 MB
    float*  z2p    = (float*)(W + 81788928);       //  4.2 MB (alias z1p)
    ushort* z1b    = (ushort*)(W + 98566144);      //  0.5 MB
    float*  z2     = (float*)(W + 99090432);       //  1.0 MB
    float*  y2     = (float*)(W + 100139008);      //  24.6 KB
    float*  adjr   = (float*)(W + 100163584);      //   1 KB
    float*  chebb  = (float*)(W + 100164608);      //   4 KB
    ushort* G      = (ushort*)(W + 100663296);     // 25.2 MB
    ushort* h0     = (ushort*)(W + 125829120);     //  2.1 MB
    ushort* h1     = (ushort*)(W + 127926272);     //  2.1 MB
    ushort* wihB   = (ushort*)(W + 130023424);     //  1.6 MB
    ushort* whhB   = (ushort*)(W + 131596288);     //  1.6 MB
    ushort* gw0    = (ushort*)(W + 133169152);     //  0.5 MB
    ushort* gw1    = (ushort*)(W + 133693440);     //  0.5 MB
    ushort* f1t    = (ushort*)(W + 134217728);     //  6.3 MB
    ushort* f2t    = (ushort*)(W + 140509184);     //  0.5 MB
    float*  biasc  = (float*)(W + 141033472);      //  6 KB

    // ---- conversions ----
    hipMemsetAsync(h0, 0, (size_t)Nn * Ff * sizeof(ushort), stream);
    cvt_x<<<(Mx * 64) / 256, 256, 0, stream>>>(x, xb);
    cvt_mat<<<(Gg * Ff / 8) / 256, 256, 0, stream>>>(wih, wihB);
    cvt_mat<<<(Gg * Ff / 8) / 256, 256, 0, stream>>>(whh, whhB);
    bias_combo<<<6, 256, 0, stream>>>(bih, bhh, biasc);
    tcvt<<<dim3(16, 16), 256, 0, stream>>>(gcnw, gw0, 512, 512);
    tcvt<<<dim3(16, 16), 256, 0, stream>>>(gcnw + 262144, gw1, 512, 512);
    tcvt<<<dim3(16, 192), 256, 0, stream>>>(f1w, f1t, 6144, 512);
    tcvt<<<dim3(16, 16), 256, 0, stream>>>(f2w, f2t, 512, 512);

    // ---- xW precompute (biases folded into columns) ----
    mfma_gemm<<<dim3(2304, 1), 256, 0, stream>>>(
        xb, wihB, nullptr, xw, biasc, Gg, Ff, Ff, 0, 192);

    // ---- GRU: 12 fused steps, h ping-pong ----
    ushort* hp = h0; ushort* hq = h1;
    for (int t = 0; t < Cc; ++t) {
        gru_fused<<<512, 256, 0, stream>>>(hp, whhB, xw, bhh, hq, G, t);
        ushort* tmp = hp; hp = hq; hq = tmp;
    }

    // ---- graph learning ----
    conv01<<<(Bb * Cc * 64) / 256, 256, 0, stream>>>(G, c0w, c0b, c1w, c1b, y2);
    conv2_mean<<<Cc * Cc, 256, 0, stream>>>(y2, c2w, c2b, adjr);
    build_cheb<<<1, 256, 0, stream>>>(adjr, chebb);

    // ---- GCN layer 1 ----
    mfma_gemm<<<dim3(768, 1), 256, 0, stream>>>(
        G, gw0, nullptr, S, nullptr, Ff, Ff, Ff, 0, 192);
    gcn_epi1<<<(Bb * Cc * Ff) / 256, 256, 0, stream>>>(S, chebb, gcnb, G, H1);

    // ---- GCN layer 2 + pool ----
    mfma_gemm<<<dim3(768, 1), 256, 0, stream>>>(
        H1, gw1, nullptr, S, nullptr, Ff, Ff, Ff, 0, 192);
    gcn_epi2<<<(Bb * Cc * Ff) / 256, 256, 0, stream>>>(S, chebb, gcnb + Ff, G, H1, pooled);

    // ---- head ----
    mfma_gemm<<<dim3(16, 16), 256, 0, stream>>>(          // fc1 split-K 16
        pooled, f1t, z1p, nullptr, nullptr, 512, Cc * Ff, 384, 262144, 4);
    fc_epi<<<1024, 256, 0, stream>>>(z1p, 16, f1b, bn1g, bn1b, bn1m, bn1v, z1b, nullptr);
    mfma_gemm<<<dim3(16, 4), 256, 0, stream>>>(           // fc2 split-K 4
        z1b, f2t, z2p, nullptr, nullptr, 512, 512, 128, 262144, 4);
    fc_epi<<<1024, 256, 0, stream>>>(z2p, 4, f2b_, bn2g, bn2b, bn2m, bn2v, nullptr, z2);
    fc3_kernel<<<(Bb * 4) / 256, 256, 0, stream>>>(z2, f3w, f3b, (float*)d_out);
}

// Round 4
// 493.538 us; speedup vs baseline: 4.6919x; 1.0591x over previous
//
#include <hip/hip_runtime.h>
#include <cmath>

// ---- problem constants ----
constexpr int Bb  = 512;
constexpr int Cc  = 12;
constexpr int Ww  = 4;
constexpr int Ff  = 512;
constexpr int Nn  = Bb * Ww;        // 2048
constexpr int Gg  = 3 * Ff;         // 1536
constexpr int Mx  = Nn * Cc;        // 24576

typedef __attribute__((ext_vector_type(8))) short bf16x8;
typedef __attribute__((ext_vector_type(4))) float f32x4;

__device__ __forceinline__ float sigm(float v) { return 1.f / (1.f + expf(-v)); }
__device__ __forceinline__ float b2f(ushort u) { union { float f; unsigned i; } v; v.i = ((unsigned)u) << 16; return v.f; }
__device__ __forceinline__ ushort f2b(float f) {
    union { float f; unsigned i; } v; v.f = f;
    unsigned r = v.i + 0x7FFFu + ((v.i >> 16) & 1u);
    return (ushort)(r >> 16);
}
__device__ __forceinline__ void async16(const ushort* g, ushort* l) {
    __builtin_amdgcn_global_load_lds(
        (const __attribute__((address_space(1))) unsigned int*)g,
        (__attribute__((address_space(3))) unsigned int*)l, 16, 0, 0);
}

// =============== generic bf16 MFMA GEMM ===============
// C[M,N] = A[M,K] @ Bt[N,K]^T.  Block 128x128, 4 waves.
// 1D grid: by = l % gridY (M-block fastest; gridY%8==0 keeps same-A blocks on one XCD).
// Epilogue uses SWAPPED operands: mfma(b,a) -> lane holds 4 consecutive columns
// per acc reg => packed 8B bf16 stores / 16B fp32 stores.
__global__ __launch_bounds__(256) void mfma_gemm(
    const ushort* __restrict__ A, const ushort* __restrict__ Bt,
    float* __restrict__ Cf, ushort* __restrict__ Cb,
    const float* __restrict__ colBias,
    int N, int K, int kLen, int MN, int gridY)
{
    __shared__ ushort As[128 * 64], Bs[128 * 64];
    const int tid = threadIdx.x;
    const int ln = tid & 63, wv = tid >> 6;
    const int l = blockIdx.x;
    const int by = l % gridY, bx = l / gridY, bz = blockIdx.y;
    const int srow = ln >> 3;
    const int kslot = (ln & 7) ^ srow;
    const int rowA0 = by * 128 + wv * 32;
    const int rowB0 = bx * 128 + wv * 32;
    const ushort* ga = A  + (long)(rowA0 + srow) * K + bz * kLen + kslot * 8;
    const ushort* gb = Bt + (long)(rowB0 + srow) * K + bz * kLen + kslot * 8;
    ushort* la = As + wv * 32 * 64;
    ushort* lb = Bs + wv * 32 * 64;
    const int rbase = (wv >> 1) * 64, cbase = (wv & 1) * 64;
    const int mrow = ln & 15, quad = ln >> 4;

    f32x4 acc[4][4] = {};

    for (int kc = 0; kc < kLen; kc += 64) {
        #pragma unroll
        for (int i = 0; i < 4; ++i) {
            async16(ga + (long)(i * 8) * K, la + i * 8 * 64);
            async16(gb + (long)(i * 8) * K, lb + i * 8 * 64);
        }
        ga += 64; gb += 64;
        __syncthreads();
        #pragma unroll
        for (int s = 0; s < 2; ++s) {
            const int sw = (((s << 2) + quad) ^ (ln & 7)) << 3;
            bf16x8 af[4], bf[4];
            #pragma unroll
            for (int i = 0; i < 4; ++i)
                af[i] = *(const bf16x8*)(As + (rbase + i * 16 + mrow) * 64 + sw);
            #pragma unroll
            for (int j = 0; j < 4; ++j)
                bf[j] = *(const bf16x8*)(Bs + (cbase + j * 16 + mrow) * 64 + sw);
            #pragma unroll
            for (int i = 0; i < 4; ++i)
                #pragma unroll
                for (int j = 0; j < 4; ++j)   // swapped: lane gets row=A(mrow), 4 consecutive cols
                    acc[i][j] = __builtin_amdgcn_mfma_f32_16x16x32_bf16(bf[j], af[i], acc[i][j], 0, 0, 0);
        }
        __syncthreads();
    }

    const int gr0 = by * 128 + rbase + mrow;          // + i*16
    const int gc0 = bx * 128 + cbase + quad * 4;      // + j*16, 4 consecutive
    if (Cb) {
        #pragma unroll
        for (int i = 0; i < 4; ++i) {
            const long rowoff = (long)(gr0 + i * 16) * N;
            #pragma unroll
            for (int j = 0; j < 4; ++j) {
                float c0 = 0.f, c1 = 0.f, c2 = 0.f, c3 = 0.f;
                if (colBias) {
                    const float4 cb4 = *(const float4*)(colBias + gc0 + j * 16);
                    c0 = cb4.x; c1 = cb4.y; c2 = cb4.z; c3 = cb4.w;
                }
                union { ushort u[4]; uint2 v; } pk;
                pk.u[0] = f2b(acc[i][j][0] + c0);
                pk.u[1] = f2b(acc[i][j][1] + c1);
                pk.u[2] = f2b(acc[i][j][2] + c2);
                pk.u[3] = f2b(acc[i][j][3] + c3);
                *(uint2*)&Cb[rowoff + gc0 + j * 16] = pk.v;
            }
        }
    } else {
        float* Co = Cf + (long)bz * MN;
        #pragma unroll
        for (int i = 0; i < 4; ++i) {
            const long rowoff = (long)(gr0 + i * 16) * N;
            #pragma unroll
            for (int j = 0; j < 4; ++j)
                *(f32x4*)&Co[rowoff + gc0 + j * 16] = acc[i][j];
        }
    }
}

// =============== fused GRU step (dual GEMM: h@Whh^T and x_t@Wih^T) ===============
// Block: 64 rows x 32 f (x3 gates = 96 cols). Grid 512 = 32 mb x 16 fb.
__global__ __launch_bounds__(256) void gru_fused(
    const ushort* __restrict__ hin, const ushort* __restrict__ xb,
    const ushort* __restrict__ whhB, const ushort* __restrict__ wihB,
    const float* __restrict__ bih, const float* __restrict__ bhh,
    ushort* __restrict__ hout, ushort* __restrict__ G, int t)
{
    __shared__ ushort Ah[64 * 64], Ax[64 * 64], Bh[96 * 64], Bx[96 * 64];
    const int tid = threadIdx.x, ln = tid & 63, wv = tid >> 6;
    const int mb = blockIdx.x & 31, fb = blockIdx.x >> 5;
    const int srow = ln >> 3, kslot = (ln & 7) ^ srow;
    const int mrow = ln & 15, quad = ln >> 4;
    f32x4 aH[6] = {}, aX[6] = {};
    const ushort* hrow = hin + (long)(mb * 64) * 512;

    for (int kc = 0; kc < 512; kc += 64) {
        #pragma unroll
        for (int a = 0; a < 2; ++a) {
            const int r0 = (wv * 2 + a) * 8;
            async16(hrow + (long)(r0 + srow) * 512 + kc + kslot * 8, Ah + r0 * 64);
            async16(xb + ((long)(mb * 64 + r0 + srow) * 12 + t) * 512 + kc + kslot * 8, Ax + r0 * 64);
        }
        #pragma unroll
        for (int b8 = 0; b8 < 3; ++b8) {
            const int lr0 = (wv * 3 + b8) * 8;
            const int lr = lr0 + srow;
            const int g = lr >> 5, fc = lr & 31;
            const long wr = (long)(g * 512 + fb * 32 + fc) * 512 + kc + kslot * 8;
            async16(whhB + wr, Bh + lr0 * 64);
            async16(wihB + wr, Bx + lr0 * 64);
        }
        __syncthreads();
        #pragma unroll
        for (int s = 0; s < 2; ++s) {
            const int sw = (((s << 2) + quad) ^ (ln & 7)) << 3;
            const bf16x8 ah = *(const bf16x8*)(Ah + (wv * 16 + mrow) * 64 + sw);
            const bf16x8 ax = *(const bf16x8*)(Ax + (wv * 16 + mrow) * 64 + sw);
            #pragma unroll
            for (int jt = 0; jt < 6; ++jt) {
                const bf16x8 bh = *(const bf16x8*)(Bh + (jt * 16 + mrow) * 64 + sw);
                aH[jt] = __builtin_amdgcn_mfma_f32_16x16x32_bf16(bh, ah, aH[jt], 0, 0, 0);
            }
            #pragma unroll
            for (int jt = 0; jt < 6; ++jt) {
                const bf16x8 bx2 = *(const bf16x8*)(Bx + (jt * 16 + mrow) * 64 + sw);
                aX[jt] = __builtin_amdgcn_mfma_f32_16x16x32_bf16(bx2, ax, aX[jt], 0, 0, 0);
            }
        }
        __syncthreads();
    }

    // lane: row n fixed (mrow); cols = jt*16 + quad*4 + r  =>  f = fb*32 + ft*16 + quad*4 + r
    const int n = mb * 64 + wv * 16 + mrow;
    #pragma unroll
    for (int ft = 0; ft < 2; ++ft) {
        const int f0 = fb * 32 + ft * 16 + quad * 4;
        const float4 bir = *(const float4*)(bih + f0);
        const float4 biz = *(const float4*)(bih + 512 + f0);
        const float4 bin = *(const float4*)(bih + 1024 + f0);
        const float4 bhr = *(const float4*)(bhh + f0);
        const float4 bhz = *(const float4*)(bhh + 512 + f0);
        const float4 bhn = *(const float4*)(bhh + 1024 + f0);
        union { ushort u[4]; uint2 v; } hp;
        hp.v = *(const uint2*)(hin + (long)n * 512 + f0);
        const float br[4] = {bir.x + bhr.x, bir.y + bhr.y, bir.z + bhr.z, bir.w + bhr.w};
        const float bz[4] = {biz.x + bhz.x, biz.y + bhz.y, biz.z + bhz.z, biz.w + bhz.w};
        const float bn_i[4] = {bin.x, bin.y, bin.z, bin.w};
        const float bn_h[4] = {bhn.x, bhn.y, bhn.z, bhn.w};
        union { ushort u[4]; uint2 v; } o;
        #pragma unroll
        for (int r = 0; r < 4; ++r) {
            const float rr = sigm(aH[ft][r] + aX[ft][r] + br[r]);
            const float zz = sigm(aH[2 + ft][r] + aX[2 + ft][r] + bz[r]);
            const float nv = tanhf(aX[4 + ft][r] + bn_i[r] + rr * (aH[4 + ft][r] + bn_h[r]));
            o.u[r] = f2b((1.f - zz) * nv + zz * b2f(hp.u[r]));
        }
        *(uint2*)&hout[(long)n * 512 + f0] = o.v;
        *(uint2*)&G[(long)(n * 12 + t) * 512 + f0] = o.v;
    }
}

// =============== conversions ===============
__global__ __launch_bounds__(256) void cvt_x(const float* __restrict__ x, ushort* __restrict__ xb)
{
    const int idx = blockIdx.x * 256 + threadIdx.x;   // Mx*64
    const int m = idx >> 6, f8 = (idx & 63) << 3;
    const int n = m / 12, c = m - n * 12;
    const int b = n >> 2, w = n & 3;
    const float* src = x + (((b * 12 + c) * 4 + w) << 9) + f8;
    const float4 a = *(const float4*)src, q = *(const float4*)(src + 4);
    uint4 o;
    o.x = (unsigned)f2b(a.x) | ((unsigned)f2b(a.y) << 16);
    o.y = (unsigned)f2b(a.z) | ((unsigned)f2b(a.w) << 16);
    o.z = (unsigned)f2b(q.x) | ((unsigned)f2b(q.y) << 16);
    o.w = (unsigned)f2b(q.z) | ((unsigned)f2b(q.w) << 16);
    *(uint4*)(xb + (m << 9) + f8) = o;
}

// wih + whh fp32 -> bf16 (one launch)
__global__ __launch_bounds__(256) void cvt_w2(
    const float* __restrict__ wih, const float* __restrict__ whh,
    ushort* __restrict__ wihB, ushort* __restrict__ whhB)
{
    int bx = blockIdx.x;
    const float* s; ushort* d;
    if (bx < 384) { s = wih; d = wihB; } else { s = whh; d = whhB; bx -= 384; }
    const int e = (bx * 256 + threadIdx.x) << 3;
    const float4 a = *(const float4*)(s + e), q = *(const float4*)(s + e + 4);
    uint4 o;
    o.x = (unsigned)f2b(a.x) | ((unsigned)f2b(a.y) << 16);
    o.y = (unsigned)f2b(a.z) | ((unsigned)f2b(a.w) << 16);
    o.z = (unsigned)f2b(q.x) | ((unsigned)f2b(q.y) << 16);
    o.w = (unsigned)f2b(q.z) | ((unsigned)f2b(q.w) << 16);
    *(uint4*)(d + e) = o;
}

// 4 transpose-convert jobs in one launch: gw0, gw1, f1t, f2t
__global__ __launch_bounds__(256) void tcvt_all(
    const float* __restrict__ gcnw, const float* __restrict__ f1w, const float* __restrict__ f2w,
    ushort* __restrict__ gw0, ushort* __restrict__ gw1,
    ushort* __restrict__ f1t, ushort* __restrict__ f2t)
{
    int by = blockIdx.y;
    const float* src; ushort* dst; int R, C;
    if (by < 16)       { src = gcnw;          dst = gw0; R = 512;  C = 512; }
    else if (by < 32)  { src = gcnw + 262144; dst = gw1; R = 512;  C = 512; by -= 16; }
    else if (by < 224) { src = f1w;           dst = f1t; R = 6144; C = 512; by -= 32; }
    else               { src = f2w;           dst = f2t; R = 512;  C = 512; by -= 224; }
    __shared__ float tl[32][33];
    const int c0 = blockIdx.x * 32, r0 = by * 32;
    const int cx = threadIdx.x & 31, ry = threadIdx.x >> 5;
    #pragma unroll
    for (int k = 0; k < 4; ++k) tl[ry + k * 8][cx] = src[(long)(r0 + ry + k * 8) * C + c0 + cx];
    __syncthreads();
    #pragma unroll
    for (int k = 0; k < 4; ++k) dst[(long)(c0 + ry + k * 8) * R + r0 + cx] = f2b(tl[cx][ry + k * 8]);
}

// =============== graph-learning ===============
__global__ __launch_bounds__(256) void conv01(
    const ushort* __restrict__ G, const float* __restrict__ w0, const float* __restrict__ b0,
    const float* __restrict__ w1, const float* __restrict__ b1, float* __restrict__ y2)
{
    const int row = (blockIdx.x * 256 + threadIdx.x) >> 6;   // b*12+c
    const int lane = threadIdx.x & 63;
    const int b = row / 12, c = row - 12 * b;
    const float w00 = w0[0], w01 = w0[1], w02 = w0[2], w03 = w0[3], bb = b0[0];
    const ushort* gp = G + ((long)(b * 4) * 12 + c) * 512;
    float s = 0.f;
    for (int f = lane; f < 512; f += 64) {
        const float v = bb + b2f(gp[f]) * w00 + b2f(gp[6144 + f]) * w01
                      + b2f(gp[12288 + f]) * w02 + b2f(gp[18432 + f]) * w03;
        s += fmaxf(v, 0.f) * w1[f];
    }
    #pragma unroll
    for (int off = 32; off; off >>= 1) s += __shfl_down(s, off);
    if (lane == 0) y2[row] = fmaxf(s + b1[0], 0.f);
}

// conv2 + relu + batch-mean + adjacency -> Laplacian -> Chebyshev, single block
__global__ __launch_bounds__(256) void conv2_cheb(
    const float* __restrict__ y2, const float* __restrict__ w2,
    const float* __restrict__ b2, float* __restrict__ cheb)
{
    __shared__ float ys[6144];
    __shared__ float adj[144], deg[12], dhat[12], lap[144], T2[144];
    const int tid = threadIdx.x;
    for (int i = tid; i < 6144; i += 256) ys[i] = y2[i];
    __syncthreads();
    if (tid < 144) {
        float wk[12];
        #pragma unroll
        for (int c = 0; c < 12; ++c) wk[c] = w2[tid * 12 + c];
        const float bias = b2[tid];
        float s = 0.f;
        for (int b = 0; b < 512; ++b) {
            float v = bias;
            #pragma unroll
            for (int c = 0; c < 12; ++c) v += ys[b * 12 + c] * wk[c];
            s += fmaxf(v, 0.f);
        }
        adj[tid] = fmaxf(s * (1.f / 512.f), 0.f);
    }
    __syncthreads();
    if (tid < 12) {
        float s = 0.f;
        for (int j = 0; j < 12; ++j) s += adj[tid * 12 + j];
        deg[tid] = s; dhat[tid] = 1.f / (sqrtf(s) + 1e-7f);
    }
    __syncthreads();
    if (tid < 144) {
        const int i = tid / 12, j = tid % 12;
        const float as = 0.5f * (adj[i * 12 + j] + adj[j * 12 + i]);
        lap[tid] = dhat[i] * ((i == j ? deg[i] : 0.f) - as) * dhat[j];
    }
    __syncthreads();
    if (tid < 144) {
        const int i = tid / 12, j = tid % 12;
        float s = 0.f;
        for (int kk = 0; kk < 12; ++kk) s += lap[i * 12 + kk] * lap[kk * 12 + j];
        T2[tid] = 2.f * s;
    }
    __syncthreads();
    if (tid < 144) {
        const int i = tid / 12, j = tid % 12;
        float s = 0.f;
        for (int kk = 0; kk < 12; ++kk) s += lap[i * 12 + kk] * T2[kk * 12 + j];
        cheb[tid] = 0.f;
        cheb[144 + tid] = lap[tid];
        cheb[288 + tid] = T2[tid];
        cheb[432 + tid] = 2.f * s - lap[tid];
    }
}

// =============== GCN epilogues ===============
__global__ __launch_bounds__(256) void gcn_epi1(
    const ushort* __restrict__ S, const float* __restrict__ cheb,
    const float* __restrict__ gcnb, const ushort* __restrict__ G,
    ushort* __restrict__ H1)
{
    __shared__ float ch[576];
    const int tid = threadIdx.x;
    for (int i = tid; i < 576; i += 256) ch[i] = cheb[i];
    __syncthreads();
    const int idx = blockIdx.x * 256 + tid;
    const int f = idx & 511, bc = idx >> 9;
    const int b = bc / 12, c = bc - 12 * b;
    const float bias = gcnb[f];
    #pragma unroll
    for (int w = 0; w < 4; ++w) {
        float o = bias;
        const ushort* Sr = S + ((b * 4 + w) * 12) * 512 + f;
        const float* cw = ch + w * 144 + c * 12;
        #pragma unroll
        for (int j = 0; j < 12; ++j) o += cw[j] * b2f(Sr[j * 512]);
        const int gi = ((b * 4 + w) * 12 + c) * 512 + f;
        H1[gi] = f2b(fmaxf(o, 0.f) + b2f(G[gi]));
    }
}

__global__ __launch_bounds__(256) void gcn_epi2(
    const ushort* __restrict__ S, const float* __restrict__ cheb,
    const float* __restrict__ gcnb, const ushort* __restrict__ G,
    const ushort* __restrict__ H1, ushort* __restrict__ pooled)
{
    __shared__ float ch[576];
    const int tid = threadIdx.x;
    for (int i = tid; i < 576; i += 256) ch[i] = cheb[i];
    __syncthreads();
    const int idx = blockIdx.x * 256 + tid;
    const int f = idx & 511, bc = idx >> 9;
    const int b = bc / 12, c = bc - 12 * b;
    const float bias = gcnb[f];
    float acc = 0.f;
    #pragma unroll
    for (int w = 0; w < 4; ++w) {
        float o = bias;
        const ushort* Sr = S + ((b * 4 + w) * 12) * 512 + f;
        const float* cw = ch + w * 144 + c * 12;
        #pragma unroll
        for (int j = 0; j < 12; ++j) o += cw[j] * b2f(Sr[j * 512]);
        const int gi = ((b * 4 + w) * 12 + c) * 512 + f;
        acc += fmaxf(o, 0.f) + b2f(H1[gi]) + b2f(G[gi]);
    }
    pooled[idx] = f2b(acc);
}

// =============== head epilogues ===============
__global__ __launch_bounds__(256) void fc_epi(
    const float* __restrict__ part, int nsplit, const float* __restrict__ bias,
    const float* __restrict__ g, const float* __restrict__ be,
    const float* __restrict__ mu, const float* __restrict__ var,
    ushort* __restrict__ outb, float* __restrict__ outf)
{
    const int idx = blockIdx.x * 256 + threadIdx.x;
    const int c = idx & 511;
    float s = bias[c];
    for (int k = 0; k < nsplit; ++k) s += part[k * 262144 + idx];
    s = s >= 0.f ? s : 0.01f * s;
    s = (s - mu[c]) * rsqrtf(var[c] + 1e-5f) * g[c] + be[c];
    if (outb) outb[idx] = f2b(s); else outf[idx] = s;
}

__global__ __launch_bounds__(256) void fc3_kernel(
    const float* __restrict__ z2, const float* __restrict__ w3,
    const float* __restrict__ b3, float* __restrict__ out)
{
    const int idx = blockIdx.x * 256 + threadIdx.x;
    const int m = idx >> 2, nc = idx & 3;
    float s = b3[nc];
    const float* zr = z2 + m * 512;
    for (int k = 0; k < 512; ++k) s += zr[k] * w3[k * 4 + nc];
    out[idx] = s;
}

extern "C" void kernel_launch(void* const* d_in, const int* in_sizes, int n_in,
                              void* d_out, int out_size, void* d_ws, size_t ws_size,
                              hipStream_t stream)
{
    (void)in_sizes; (void)n_in; (void)out_size; (void)ws_size;
    const float* x    = (const float*)d_in[0];
    const float* wih  = (const float*)d_in[1];
    const float* whh  = (const float*)d_in[2];
    const float* bih  = (const float*)d_in[3];
    const float* bhh  = (const float*)d_in[4];
    const float* c0w  = (const float*)d_in[5];
    const float* c0b  = (const float*)d_in[6];
    const float* c1w  = (const float*)d_in[7];
    const float* c1b  = (const float*)d_in[8];
    const float* c2w  = (const float*)d_in[9];
    const float* c2b  = (const float*)d_in[10];
    const float* gcnw = (const float*)d_in[11];
    const float* gcnb = (const float*)d_in[12];
    const float* f1w  = (const float*)d_in[13];
    const float* f1b  = (const float*)d_in[14];
    const float* bn1g = (const float*)d_in[15];
    const float* bn1b = (const float*)d_in[16];
    const float* bn1m = (const float*)d_in[17];
    const float* bn1v = (const float*)d_in[18];
    const float* f2w  = (const float*)d_in[19];
    const float* f2b_ = (const float*)d_in[20];
    const float* bn2g = (const float*)d_in[21];
    const float* bn2b = (const float*)d_in[22];
    const float* bn2m = (const float*)d_in[23];
    const float* bn2v = (const float*)d_in[24];
    const float* f3w  = (const float*)d_in[25];
    const float* f3b  = (const float*)d_in[26];

    // ---- workspace layout (bytes), aliased; total ~118 MB ----
    char* W = (char*)d_ws;
    ushort* xb     = (ushort*)(W + 0);             // 25.2 MB (dead after GRU)
    ushort* pooled = (ushort*)(W + 0);             //  6.3 MB (alias xb)
    float*  z1p    = (float*)(W + 8388608);        // 16.8 MB (alias xb tail)
    float*  z2p    = z1p;                          //  4.2 MB (alias, after z1p consumed)
    ushort* G      = (ushort*)(W + 25165824);      // 25.2 MB
    ushort* S      = (ushort*)(W + 50331648);      // 25.2 MB
    ushort* H1     = (ushort*)(W + 75497472);      // 25.2 MB
    ushort* h0     = (ushort*)(W + 100663296);     //  2.1 MB
    ushort* h1     = (ushort*)(W + 102760448);     //  2.1 MB
    ushort* wihB   = (ushort*)(W + 104857600);     //  1.6 MB
    ushort* whhB   = (ushort*)(W + 106430464);     //  1.6 MB
    ushort* gw0    = (ushort*)(W + 108003328);     //  0.5 MB
    ushort* gw1    = (ushort*)(W + 108527616);     //  0.5 MB
    ushort* f1t    = (ushort*)(W + 109051904);     //  6.3 MB
    ushort* f2t    = (ushort*)(W + 115343360);     //  0.5 MB
    ushort* z1b    = (ushort*)(W + 115867648);     //  0.5 MB
    float*  z2     = (float*)(W + 116391936);      //  1.0 MB
    float*  y2     = (float*)(W + 117440512);      //  24.6 KB
    float*  chebb  = (float*)(W + 117465088);      //  2.3 KB

    // ---- prep ----
    hipMemsetAsync(h0, 0, (size_t)Nn * Ff * sizeof(ushort), stream);
    cvt_x<<<(Mx * 64) / 256, 256, 0, stream>>>(x, xb);
    cvt_w2<<<768, 256, 0, stream>>>(wih, whh, wihB, whhB);
    tcvt_all<<<dim3(16, 240), 256, 0, stream>>>(gcnw, f1w, f2w, gw0, gw1, f1t, f2t);

    // ---- GRU: 12 fused dual-GEMM steps, h ping-pong ----
    ushort* hp = h0; ushort* hq = h1;
    for (int t = 0; t < Cc; ++t) {
        gru_fused<<<512, 256, 0, stream>>>(hp, xb, whhB, wihB, bih, bhh, hq, G, t);
        ushort* tmp = hp; hp = hq; hq = tmp;
    }

    // ---- graph learning ----
    conv01<<<(Bb * Cc * 64) / 256, 256, 0, stream>>>(G, c0w, c0b, c1w, c1b, y2);
    conv2_cheb<<<1, 256, 0, stream>>>(y2, c2w, c2b, chebb);

    // ---- GCN layer 1 ----
    mfma_gemm<<<dim3(768, 1), 256, 0, stream>>>(
        G, gw0, nullptr, S, nullptr, Ff, Ff, Ff, 0, 192);
    gcn_epi1<<<(Bb * Cc * Ff) / 256, 256, 0, stream>>>(S, chebb, gcnb, G, H1);

    // ---- GCN layer 2 + pool ----
    mfma_gemm<<<dim3(768, 1), 256, 0, stream>>>(
        H1, gw1, nullptr, S, nullptr, Ff, Ff, Ff, 0, 192);
    gcn_epi2<<<(Bb * Cc * Ff) / 256, 256, 0, stream>>>(S, chebb, gcnb + Ff, G, H1, pooled);

    // ---- head ----
    mfma_gemm<<<dim3(16, 16), 256, 0, stream>>>(          // fc1 split-K 16
        pooled, f1t, z1p, nullptr, nullptr, 512, Cc * Ff, 384, 262144, 4);
    fc_epi<<<1024, 256, 0, stream>>>(z1p, 16, f1b, bn1g, bn1b, bn1m, bn1v, z1b, nullptr);
    mfma_gemm<<<dim3(16, 4), 256, 0, stream>>>(           // fc2 split-K 4
        z1b, f2t, z2p, nullptr, nullptr, 512, 512, 128, 262144, 4);
    fc_epi<<<1024, 256, 0, stream>>>(z2p, 4, f2b_, bn2g, bn2b, bn2m, bn2v, nullptr, z2);
    fc3_kernel<<<(Bb * 4) / 256, 256, 0, stream>>>(z2, f3w, f3b, (float*)d_out);
}